// Round 8
// baseline (670.933 us; speedup 1.0000x reference)
//
#include <hip/hip_runtime.h>

// Problem constants (match reference).
#define BB 32
#define MM 2048
#define NN 2048
#define ROWS 64          // rows of A per block
#define CHUNKS (MM / ROWS)   // 32 blocks per batch; also partial count
#define THREADS 256      // 4 waves

typedef float f32x4 __attribute__((ext_vector_type(4)));

// ws layout (floats), all written-before-read (no zeroing needed):
//   [0, P0)           : At_lambda partials, [b][j][col]   (8 MB)
//   [P0, P0+2048)     : per-fused-block {pr, cm} pairs (BB*CHUNKS = 1024)
//   [P1, P1+512)      : per-finalize-block {stat, dual} pairs (256)
#define P0 ((size_t)BB * CHUNKS * NN)
#define P1 (P0 + 2 * BB * CHUNKS)
#define FIN_BLOCKS 256

__device__ __forceinline__ float waveReduceSum(float v) {
#pragma unroll
    for (int off = 32; off > 0; off >>= 1)
        v += __shfl_down(v, off, 64);
    return v;  // valid in lane 0
}

// DPP row_shr add: pure VALU, no DS pipe. After shr 1,2,4,8 the lane with
// (lane&15)==15 holds the sum of its 16-lane group.
template <int CTRL>
__device__ __forceinline__ float dppAdd(float v) {
    int s = __builtin_amdgcn_update_dpp(0, __builtin_bit_cast(int, v),
                                        CTRL, 0xF, 0xF, false);
    return v + __builtin_bit_cast(float, s);
}

__device__ __forceinline__ float group16Reduce(float v) {
    v = dppAdd<0x111>(v);  // row_shr:1
    v = dppAdd<0x112>(v);  // row_shr:2
    v = dppAdd<0x114>(v);  // row_shr:4
    v = dppAdd<0x118>(v);  // row_shr:8
    return v;              // valid in lane (t&15)==15
}

// fused_main, R8: ROW-INTERLEAVED block mapping.
// Theory: read BW has been pinned at 1.8-1.95 TB/s in every config while
// write/fill traffic hits 6.4 TB/s. The dense patterns (fill, copy ubench)
// keep the chip's INSTANTANEOUS footprint one contiguous sliding window;
// slab-per-block fragments it into 1024 scattered 8KB windows -> DRAM
// row-buffer thrash. Fix: block j of batch b owns rows m = j + 32*r, so at
// lockstep iteration r each batch's 32 blocks read one contiguous 256 KB
// window (32 dense windows chip-wide instead of 1024 scattered ones).
// Accumulator structure, ws layout, and finalize are unchanged.
__global__ __launch_bounds__(THREADS, 4) void fused_main(
    const float* __restrict__ x_hat, const float* __restrict__ lam_hat,
    const float* __restrict__ A, const float* __restrict__ b_pad,
    float* __restrict__ ws) {
    const int b = blockIdx.y;
    const int j = blockIdx.x;            // 0..CHUNKS-1, row residue class
    const int t = threadIdx.x;

    __shared__ float lamS[ROWS];
    __shared__ __align__(16) float wp[ROWS * 16];

    // lam for this block's rows: m = j + 32*r  (strided gather, once).
    if (t < ROWS) lamS[t] = lam_hat[b * MM + j + CHUNKS * t];
    __syncthreads();

    const f32x4* xv = (const f32x4*)(x_hat + (size_t)b * NN);
    const f32x4 x0 = xv[t];
    const f32x4 x1 = xv[256 + t];

    f32x4 at0 = (f32x4)(0.f);
    f32x4 at1 = (f32x4)(0.f);

    const int RV = NN / 4;  // row stride in f32x4 (512)
    const f32x4* Ab = (const f32x4*)(A + (size_t)b * MM * NN);

    // Prologue: row j in flight.
    const f32x4* p0 = Ab + (size_t)j * RV;
    f32x4 a0 = __builtin_nontemporal_load(p0 + t);
    f32x4 a1 = __builtin_nontemporal_load(p0 + 256 + t);

#define ROW_BODY(r)                                              \
    do {                                                         \
        const float lm = lamS[r];                                \
        f32x4 d = a0 * x0 + a1 * x1;                             \
        at0 += a0 * lm;                                          \
        at1 += a1 * lm;                                          \
        float dot = (d.x + d.y) + (d.z + d.w);                   \
        dot = group16Reduce(dot);                                \
        if ((t & 15) == 15) wp[(r) * 16 + (t >> 4)] = dot;       \
    } while (0)

    for (int r = 0; r < ROWS - 1; ++r) {
        // Prefetch next interleaved row: m = j + 32*(r+1).
        const f32x4* np = Ab + (size_t)(j + CHUNKS * (r + 1)) * RV;
        f32x4 n0 = __builtin_nontemporal_load(np + t);
        f32x4 n1 = __builtin_nontemporal_load(np + 256 + t);

        ROW_BODY(r);

        a0 = n0;
        a1 = n1;
    }
    ROW_BODY(ROWS - 1);  // peeled
#undef ROW_BODY
    __syncthreads();

    // Wave 0 finalizes: iteration-index t <-> row m = j + 32*t.
    if (t < 64) {
        const f32x4* wpv = (const f32x4*)wp;
        f32x4 s4 = wpv[t * 4 + 0] + wpv[t * 4 + 1] +
                   wpv[t * 4 + 2] + wpv[t * 4 + 3];
        float y = (s4.x + s4.y) + (s4.z + s4.w)
                - b_pad[b * MM + j + CHUNKS * t];
        float lm = lamS[t];
        float ry = fmaxf(y, 0.f);
        float pr = ry * ry;
        float c = lm * y;
        float cm = c * c;
        pr = waveReduceSum(pr);
        cm = waveReduceSum(cm);
        if (t == 0) {
            float* prcm = ws + P0 + ((size_t)b * CHUNKS + j) * 2;
            prcm[0] = pr;
            prcm[1] = cm;
        }
    }

    // Private-slice flush of the At_lambda partial (coalesced, no atomics).
    f32x4* dst = (f32x4*)(ws + ((size_t)b * CHUNKS + j) * NN);
    dst[t] = at0;
    dst[256 + t] = at1;
}

// finalize_partial (R6 version): 256 blocks (1/CU). Block = (b, colgroup of
// 256 floats). Thread = (colvec c in [0,64), k-quarter kq in [0,4)): 8
// independent f32x4 loads, LDS combine of the 4 k-quarters, vectorized dual.
__global__ __launch_bounds__(256) void finalize_partial(
    const float* __restrict__ ws_ro, const float* __restrict__ c_pad,
    const float* __restrict__ lam_hat, float* __restrict__ ws) {
    const int t = threadIdx.x;
    const int b = blockIdx.x >> 3;        // 32 batches
    const int g = blockIdx.x & 7;         // 8 col-groups of 256 floats
    const int c = t & 63;                 // f32x4 colvec within group
    const int kq = t >> 6;                // k-quarter (0..3)

    const f32x4* base = (const f32x4*)ws_ro +
        ((size_t)b * CHUNKS + (size_t)kq * 8) * (NN / 4) + (size_t)g * 64 + c;
    f32x4 s = (f32x4)(0.f);
#pragma unroll
    for (int k = 0; k < 8; ++k) s += base[(size_t)k * (NN / 4)];

    __shared__ __align__(16) f32x4 part[4][64];
    part[kq][c] = s;
    __syncthreads();

    float stat = 0.f, dual = 0.f;
    if (t < 64) {
        f32x4 v = part[0][c] + part[1][c] + part[2][c] + part[3][c];
        f32x4 cp = ((const f32x4*)c_pad)[(size_t)b * (NN / 4) + (size_t)g * 64 + c];
        v += cp;
        stat = v.x * v.x + v.y * v.y + v.z * v.z + v.w * v.w;

        f32x4 l = ((const f32x4*)lam_hat)[(size_t)blockIdx.x * 64 + c];
        float r0 = fmaxf(-l.x, 0.f), r1 = fmaxf(-l.y, 0.f);
        float r2 = fmaxf(-l.z, 0.f), r3 = fmaxf(-l.w, 0.f);
        dual = r0 * r0 + r1 * r1 + r2 * r2 + r3 * r3;

        stat = waveReduceSum(stat);
        dual = waveReduceSum(dual);
        if (t == 0) {
            ws[P1 + (size_t)blockIdx.x * 2 + 0] = stat;
            ws[P1 + (size_t)blockIdx.x * 2 + 1] = dual;
        }
    }
}

// combine: reduce 256 {stat,dual} pairs (P1) and 1024 {pr,cm} pairs (P0),
// apply loss weights. One block, 4 waves: one category per wave.
__global__ __launch_bounds__(256) void combine_kernel(
    const float* __restrict__ ws_ro, float* __restrict__ out) {
    const int t = threadIdx.x;
    const int wave = t >> 6;   // 0=stat 1=dual 2=pr 3=cm
    const int lane = t & 63;
    float v = 0.f;
    if (wave == 0) {
#pragma unroll
        for (int j = 0; j < 4; ++j)
            v += ws_ro[P1 + (size_t)((lane << 2) | j) * 2 + 0];
    } else if (wave == 1) {
#pragma unroll
        for (int j = 0; j < 4; ++j)
            v += ws_ro[P1 + (size_t)((lane << 2) | j) * 2 + 1];
    } else if (wave == 2) {
#pragma unroll
        for (int j = 0; j < 16; ++j)
            v += ws_ro[P0 + (size_t)((lane << 4) | j) * 2 + 0];
    } else {
#pragma unroll
        for (int j = 0; j < 16; ++j)
            v += ws_ro[P0 + (size_t)((lane << 4) | j) * 2 + 1];
    }
    v = waveReduceSum(v);
    __shared__ float s[4];
    if (lane == 0) s[wave] = v;
    __syncthreads();
    if (t == 0) {
        const float invBM = 1.0f / (float)(BB * MM);
        const float invBN = 1.0f / (float)(BB * NN);
        float stat = s[0] * invBN;
        float dual = s[1] * invBM;
        float primal = s[2] * invBM;
        float comp = s[3] * invBM;
        out[0] = 0.1f * primal + 0.1f * dual + 0.6f * stat + 0.2f * comp;
    }
}

extern "C" void kernel_launch(void* const* d_in, const int* in_sizes, int n_in,
                              void* d_out, int out_size, void* d_ws, size_t ws_size,
                              hipStream_t stream) {
    const float* x_hat   = (const float*)d_in[0];
    const float* lam_hat = (const float*)d_in[1];
    const float* A       = (const float*)d_in[2];
    const float* b_pad   = (const float*)d_in[3];
    const float* c_pad   = (const float*)d_in[4];
    // d_in[5]/d_in[6] (masks) unused by the reference forward.
    float* out = (float*)d_out;
    float* ws = (float*)d_ws;

    dim3 grid(CHUNKS, BB);
    fused_main<<<grid, THREADS, 0, stream>>>(x_hat, lam_hat, A, b_pad, ws);

    finalize_partial<<<FIN_BLOCKS, 256, 0, stream>>>(ws, c_pad, lam_hat, ws);

    combine_kernel<<<1, 256, 0, stream>>>(ws, out);
}